// Round 12
// baseline (194.717 us; speedup 1.0000x reference)
//
#include <hip/hip_runtime.h>

#define NPTS 262144
#define HID  20
#define NMID 8

typedef float f32x16 __attribute__((ext_vector_type(16)));
typedef short short8 __attribute__((ext_vector_type(8)));
typedef unsigned int u32;

__device__ __forceinline__ u32 bf16_bits(float f) {
    u32 u = __builtin_bit_cast(u32, f);
    return (u + 0x7FFFu + ((u >> 16) & 1u)) >> 16;   // RNE (weight staging only)
}

// Round-half-up bf16 pair pack: 2 adds + 1 byte-perm. Result = bf16(a) | bf16(b)<<16.
__device__ __forceinline__ u32 pk2(float a, float b) {
    u32 ua = __builtin_bit_cast(u32, a) + 0x8000u;
    u32 ub = __builtin_bit_cast(u32, b) + 0x8000u;
    return __builtin_amdgcn_perm(ub, ua, 0x07060302u);  // bytes: ua[2],ua[3],ub[2],ub[3]
}

__device__ __forceinline__ float flo(u32 c) { return __builtin_bit_cast(float, c << 16); }
__device__ __forceinline__ float fhi(u32 c) { return __builtin_bit_cast(float, c & 0xFFFF0000u); }

__device__ __forceinline__ short8 mk_frag(const u32* d, int o) {
    uint4 v = make_uint4(d[o + 0], d[o + 1], d[o + 2], d[o + 3]);
    return __builtin_bit_cast(short8, v);
}

// Weight k-columns PERMUTED at staging (k -> k^12 for k in [4,12)) so the needed
// B-fragment equals the LOCAL C/D register order for both lane halves — no
// cross-lane ops. (hi-lane s=1 slots are k=24..31 where A columns are zero.)
// H stream: hi + lo-residual fragments (full 3-term expansion).
__device__ __forceinline__ void build_frags_hl(const float* v, u32 bias,
                                               u32* bh, u32* bl) {
    u32 h01 = pk2(v[0], v[1]),   h23 = pk2(v[2], v[3]);
    u32 h45 = pk2(v[4], v[5]),   h67 = pk2(v[6], v[7]);
    u32 h89 = pk2(v[8], v[9]),   hAB = pk2(v[10], v[11]);
    bh[0] = h01; bh[1] = h23; bh[2] = h45; bh[3] = h67;
    bh[4] = h89; bh[5] = hAB; bh[6] = bias; bh[7] = 0u;
    bl[0] = pk2(v[0] - flo(h01), v[1] - fhi(h01));
    bl[1] = pk2(v[2] - flo(h23), v[3] - fhi(h23));
    bl[2] = pk2(v[4] - flo(h45), v[5] - fhi(h45));
    bl[3] = pk2(v[6] - flo(h67), v[7] - fhi(h67));
    bl[4] = pk2(v[8] - flo(h89), v[9] - fhi(h89));
    bl[5] = pk2(v[10] - flo(hAB), v[11] - fhi(hAB));
    bl[6] = 0u; bl[7] = 0u;
}

// Derivative streams (T/X/Q): single-bf16 activation fragment; weights remain
// hi/lo-exact, so per-layer relative error ~2^-9 on derivative streams only.
__device__ __forceinline__ void build_frags_s(const float* v, u32* bh) {
    bh[0] = pk2(v[0], v[1]);   bh[1] = pk2(v[2], v[3]);
    bh[2] = pk2(v[4], v[5]);   bh[3] = pk2(v[6], v[7]);
    bh[4] = pk2(v[8], v[9]);   bh[5] = pk2(v[10], v[11]);
    bh[6] = 0u; bh[7] = 0u;
}

#define MF(A, D, O, C) __builtin_amdgcn_mfma_f32_32x32x16_bf16(A, mk_frag(D, O), C, 0, 0, 0)

__launch_bounds__(256, 6)
__global__ void pde_mfma_kernel(const float* __restrict__ x,
                                const float* __restrict__ W_in,
                                const float* __restrict__ b_in,
                                const float* __restrict__ W_mid,
                                const float* __restrict__ b_mid,
                                const float* __restrict__ W_out,
                                const float* __restrict__ b_out,
                                float* __restrict__ out) {
    // A-frags, 3 parts/layer (24 KB total):
    //   part0 = hi s=0 (full 64 lanes)
    //   part1 = MERGED s=1: lanes 0..31 = hi-s1, lanes 32..63 = lo-s1
    //           (s=1 data is non-zero only for k=16..20 -> lanes 0..19 each)
    //   part2 = lo s=0 (full 64 lanes)
    // Lanes>=32 read s=1 frags from a 16B zero block (their A rows are zero).
    __shared__ short sWf[NMID * 3 * 64 * 8];   // 24 KB
    __shared__ float sIn[2 * 16 * 4];
    __shared__ short sZero[8];

    const int tid = threadIdx.x;

    for (int idx = tid; idx < NMID * 3 * 64 * 8 / 2; idx += 256)
        ((u32*)sWf)[idx] = 0u;
    if (tid < 4) ((u32*)sZero)[tid] = 0u;
    for (int idx = tid; idx < 32; idx += 256) {
        int h2 = idx >> 4, reg = idx & 15;
        int n = (reg & 3) + 8 * (reg >> 2) + 4 * h2;
        float w0 = 0.f, w1 = 0.f, b = 0.f, wo = 0.f;
        if (n < HID) { w0 = W_in[n * 2]; w1 = W_in[n * 2 + 1]; b = b_in[n]; wo = W_out[n]; }
        sIn[idx * 4 + 0] = w0; sIn[idx * 4 + 1] = w1;
        sIn[idx * 4 + 2] = b;  sIn[idx * 4 + 3] = wo;
    }
    __syncthreads();
    for (int idx = tid; idx < NMID * HID * (HID + 1); idx += 256) {
        int layer = idx / (HID * (HID + 1));
        int rem   = idx % (HID * (HID + 1));
        int j = rem / (HID + 1);
        int k = rem % (HID + 1);
        float w = (k < HID) ? W_mid[(layer * HID + j) * HID + k] : b_mid[layer * HID + j];
        u32 whib = bf16_bits(w);
        u32 wlob = bf16_bits(w - __builtin_bit_cast(float, whib << 16));
        int kp = (k >= 4 && k < 12) ? (k ^ 12) : k;   // column permutation
        int s = kp >> 4, kk = kp & 15, h2 = kk >> 3, r = kk & 7;
        int lane = j + 32 * h2;
        if (s == 0) {
            sWf[((layer * 3 + 0) * 64 + lane) * 8 + r] = (short)whib;   // hi s0
            sWf[((layer * 3 + 2) * 64 + lane) * 8 + r] = (short)wlob;   // lo s0
        } else {
            // s=1: kk in 0..4 -> h2=0, lane=j in 0..19; merged part
            sWf[((layer * 3 + 1) * 64 + lane) * 8 + r]      = (short)whib;  // hi s1
            sWf[((layer * 3 + 1) * 64 + lane + 32) * 8 + r] = (short)wlob;  // lo s1 at lane+32
        }
    }
    __syncthreads();

    const int lane = tid & 63;
    const int wv   = tid >> 6;
    const int p    = lane & 31;
    const int hi   = lane >> 5;
    const int P    = blockIdx.x * 128 + wv * 32 + p;

    const float2 xv = reinterpret_cast<const float2*>(x)[P];
    const float x0 = xv.x, x1 = xv.y;
    const float bo = b_out[0];

    const float4* sIn4 = reinterpret_cast<const float4*>(sIn);

    float vh[12], vs[12], vt[12], vx[12], vxx[12];

    // ---- input layer (fp32, exact) ----
    #pragma unroll
    for (int r = 0; r < 12; ++r) {
        float4 t = sIn4[hi * 16 + r];
        float z = fmaf(t.x, x0, fmaf(t.y, x1, t.z));
        float e = __expf(2.0f * z);
        float a = 1.0f - __fdividef(2.0f, e + 1.0f);
        float s = fmaf(-a, a, 1.0f);
        float sx = s * t.y;
        vh[r] = a; vt[r] = s * t.x; vx[r] = sx;
        vxx[r] = -2.0f * a * sx * t.y;
    }

    const f32x16 zz = 0.0f;
    const short8* afp = reinterpret_cast<const short8*>(sWf);
    const short8* pz  = reinterpret_cast<const short8*>(sZero);

    for (int layer = 0; layer < NMID; ++layer) {
        const int base = layer * 3 * 64;
        const short8 wh0 = afp[base + lane];
        const short8 wl0 = afp[base + 128 + lane];
        const short8* ph1 = (lane < 32) ? (afp + base + 64 + lane)      : pz;
        const short8* pl1 = (lane < 32) ? (afp + base + 64 + 32 + lane) : pz;
        const short8 wh1 = *ph1;
        const short8 wl1 = *pl1;

        // ---- group 1: H (hi+lo 3-term) and T (single) ----
        {
            u32 dh[8], dhl[8], dt[8];
            build_frags_hl(vh, 0x00003F80u, dh, dhl);   // bias col: hi=1.0, lo=0.0
            build_frags_s(vt, dt);

            f32x16 aH = MF(wh0, dh, 0, zz);  f32x16 aT = MF(wh0, dt, 0, zz);
            aH = MF(wh1, dh, 4, aH);         aT = MF(wh1, dt, 4, aT);
            aH = MF(wh0, dhl, 0, aH);        aT = MF(wl0, dt, 0, aT);
            aH = MF(wh1, dhl, 4, aH);        aT = MF(wl1, dt, 4, aT);
            aH = MF(wl0, dh, 0, aH);
            aH = MF(wl1, dh, 4, aH);

            #pragma unroll
            for (int r = 0; r < 12; ++r) {
                float z = aH[r];
                float e = __expf(2.0f * z);
                float a = 1.0f - __fdividef(2.0f, e + 1.0f);
                float s = fmaf(-a, a, 1.0f);
                vh[r] = a; vs[r] = s; vt[r] = s * aT[r];
            }
        }

        // ---- group 2: X and Q streams (single) ----
        {
            u32 dx[8], dq[8];
            build_frags_s(vx, dx);
            build_frags_s(vxx, dq);

            f32x16 aX = MF(wh0, dx, 0, zz);  f32x16 aQ = MF(wh0, dq, 0, zz);
            aX = MF(wh1, dx, 4, aX);         aQ = MF(wh1, dq, 4, aQ);
            aX = MF(wl0, dx, 0, aX);         aQ = MF(wl0, dq, 0, aQ);
            aX = MF(wl1, dx, 4, aX);         aQ = MF(wl1, dq, 4, aQ);

            #pragma unroll
            for (int r = 0; r < 12; ++r) {
                float zx = aX[r];
                float a = vh[r], s = vs[r];
                float nx = s * zx;
                float t2 = 2.0f * a * nx;
                vx[r] = nx;
                vxx[r] = fmaf(-t2, zx, s * aQ[r]);
            }
        }
    }

    // ---- output layer ----
    float f = 0.f, ft = 0.f, fx = 0.f, fxx = 0.f;
    #pragma unroll
    for (int r = 0; r < 12; ++r) {
        float4 t = sIn4[hi * 16 + r];
        f   = fmaf(t.w, vh[r],  f);
        ft  = fmaf(t.w, vt[r],  ft);
        fx  = fmaf(t.w, vx[r],  fx);
        fxx = fmaf(t.w, vxx[r], fxx);
    }
    f   += __shfl_xor(f, 32);
    ft  += __shfl_xor(ft, 32);
    fx  += __shfl_xor(fx, 32);
    fxx += __shfl_xor(fxx, 32);
    f += bo;

    if (!hi) {
        const float pde = 0.5f * x1 * x1 + ft + 0.5f * fxx + 0.5f * x1 * fx
                          - 0.069444444444444f * fx * fx;
        out[P] = f;
        out[NPTS + P] = pde;
    }
}

extern "C" void kernel_launch(void* const* d_in, const int* in_sizes, int n_in,
                              void* d_out, int out_size, void* d_ws, size_t ws_size,
                              hipStream_t stream) {
    const float* x     = (const float*)d_in[0];
    const float* W_in  = (const float*)d_in[1];
    const float* b_in  = (const float*)d_in[2];
    const float* W_mid = (const float*)d_in[3];
    const float* b_mid = (const float*)d_in[4];
    const float* W_out = (const float*)d_in[5];
    const float* b_out = (const float*)d_in[6];
    float* out = (float*)d_out;

    hipLaunchKernelGGL(pde_mfma_kernel, dim3(NPTS / 128), dim3(256), 0, stream,
                       x, W_in, b_in, W_mid, b_mid, W_out, b_out, out);
}

// Round 13
// 64.899 us; speedup vs baseline: 3.0003x; 3.0003x over previous
//
#include <hip/hip_runtime.h>

#define NPTS 262144
#define HID  20
#define NMID 8

typedef float f32x16 __attribute__((ext_vector_type(16)));
typedef short short8 __attribute__((ext_vector_type(8)));
typedef unsigned int u32;

__device__ __forceinline__ u32 bf16_bits(float f) {
    u32 u = __builtin_bit_cast(u32, f);
    return (u + 0x7FFFu + ((u >> 16) & 1u)) >> 16;   // RNE (weight staging only)
}

// Round-half-up bf16 pair pack: 2 adds + 1 byte-perm. Result = bf16(a) | bf16(b)<<16.
__device__ __forceinline__ u32 pk2(float a, float b) {
    u32 ua = __builtin_bit_cast(u32, a) + 0x8000u;
    u32 ub = __builtin_bit_cast(u32, b) + 0x8000u;
    return __builtin_amdgcn_perm(ub, ua, 0x07060302u);  // bytes: ua[2],ua[3],ub[2],ub[3]
}

__device__ __forceinline__ float flo(u32 c) { return __builtin_bit_cast(float, c << 16); }
__device__ __forceinline__ float fhi(u32 c) { return __builtin_bit_cast(float, c & 0xFFFF0000u); }

__device__ __forceinline__ short8 mk_frag(const u32* d, int o) {
    uint4 v = make_uint4(d[o + 0], d[o + 1], d[o + 2], d[o + 3]);
    return __builtin_bit_cast(short8, v);
}

// Weight k-columns PERMUTED at staging (k -> k^12 for k in [4,12)) so the needed
// B-fragment equals the LOCAL C/D register order for both lane halves — no
// cross-lane ops. (hi-lane s=1 slots are k=24..31 where A columns are zero.)
// H stream: hi + lo-residual fragments (full 3-term expansion).
__device__ __forceinline__ void build_frags_hl(const float* v, u32 bias,
                                               u32* bh, u32* bl) {
    u32 h01 = pk2(v[0], v[1]),   h23 = pk2(v[2], v[3]);
    u32 h45 = pk2(v[4], v[5]),   h67 = pk2(v[6], v[7]);
    u32 h89 = pk2(v[8], v[9]),   hAB = pk2(v[10], v[11]);
    bh[0] = h01; bh[1] = h23; bh[2] = h45; bh[3] = h67;
    bh[4] = h89; bh[5] = hAB; bh[6] = bias; bh[7] = 0u;
    bl[0] = pk2(v[0] - flo(h01), v[1] - fhi(h01));
    bl[1] = pk2(v[2] - flo(h23), v[3] - fhi(h23));
    bl[2] = pk2(v[4] - flo(h45), v[5] - fhi(h45));
    bl[3] = pk2(v[6] - flo(h67), v[7] - fhi(h67));
    bl[4] = pk2(v[8] - flo(h89), v[9] - fhi(h89));
    bl[5] = pk2(v[10] - flo(hAB), v[11] - fhi(hAB));
    bl[6] = 0u; bl[7] = 0u;
}

// Derivative streams (T/X/Q): single-bf16 activation fragment; weights remain
// hi/lo-exact, so per-layer relative error ~2^-9 on derivative streams only.
__device__ __forceinline__ void build_frags_s(const float* v, u32* bh) {
    bh[0] = pk2(v[0], v[1]);   bh[1] = pk2(v[2], v[3]);
    bh[2] = pk2(v[4], v[5]);   bh[3] = pk2(v[6], v[7]);
    bh[4] = pk2(v[8], v[9]);   bh[5] = pk2(v[10], v[11]);
    bh[6] = 0u; bh[7] = 0u;
}

#define MF(A, D, O, C) __builtin_amdgcn_mfma_f32_32x32x16_bf16(A, mk_frag(D, O), C, 0, 0, 0)

__launch_bounds__(256, 4)
__global__ void pde_mfma_kernel(const float* __restrict__ x,
                                const float* __restrict__ W_in,
                                const float* __restrict__ b_in,
                                const float* __restrict__ W_mid,
                                const float* __restrict__ b_mid,
                                const float* __restrict__ W_out,
                                const float* __restrict__ b_out,
                                float* __restrict__ out) {
    // A-frags, 3 parts/layer (24 KB total):
    //   part0 = hi s=0 (full 64 lanes)
    //   part1 = MERGED s=1: lanes 0..31 = hi-s1, lanes 32..63 = lo-s1
    //           (s=1 data is non-zero only for k=16..20 -> lanes 0..19 each)
    //   part2 = lo s=0 (full 64 lanes)
    // Lanes>=32 read s=1 frags from a 16B zero block (their A rows are zero).
    __shared__ short sWf[NMID * 3 * 64 * 8];   // 24 KB
    __shared__ float sIn[2 * 16 * 4];
    __shared__ short sZero[8];

    const int tid = threadIdx.x;

    for (int idx = tid; idx < NMID * 3 * 64 * 8 / 2; idx += 256)
        ((u32*)sWf)[idx] = 0u;
    if (tid < 4) ((u32*)sZero)[tid] = 0u;
    for (int idx = tid; idx < 32; idx += 256) {
        int h2 = idx >> 4, reg = idx & 15;
        int n = (reg & 3) + 8 * (reg >> 2) + 4 * h2;
        float w0 = 0.f, w1 = 0.f, b = 0.f, wo = 0.f;
        if (n < HID) { w0 = W_in[n * 2]; w1 = W_in[n * 2 + 1]; b = b_in[n]; wo = W_out[n]; }
        sIn[idx * 4 + 0] = w0; sIn[idx * 4 + 1] = w1;
        sIn[idx * 4 + 2] = b;  sIn[idx * 4 + 3] = wo;
    }
    __syncthreads();
    for (int idx = tid; idx < NMID * HID * (HID + 1); idx += 256) {
        int layer = idx / (HID * (HID + 1));
        int rem   = idx % (HID * (HID + 1));
        int j = rem / (HID + 1);
        int k = rem % (HID + 1);
        float w = (k < HID) ? W_mid[(layer * HID + j) * HID + k] : b_mid[layer * HID + j];
        u32 whib = bf16_bits(w);
        u32 wlob = bf16_bits(w - __builtin_bit_cast(float, whib << 16));
        int kp = (k >= 4 && k < 12) ? (k ^ 12) : k;   // column permutation
        int s = kp >> 4, kk = kp & 15, h2 = kk >> 3, r = kk & 7;
        int lane = j + 32 * h2;
        if (s == 0) {
            sWf[((layer * 3 + 0) * 64 + lane) * 8 + r] = (short)whib;   // hi s0
            sWf[((layer * 3 + 2) * 64 + lane) * 8 + r] = (short)wlob;   // lo s0
        } else {
            // s=1: kk in 0..4 -> h2=0, lane=j in 0..19; merged part
            sWf[((layer * 3 + 1) * 64 + lane) * 8 + r]      = (short)whib;  // hi s1
            sWf[((layer * 3 + 1) * 64 + lane + 32) * 8 + r] = (short)wlob;  // lo s1 at lane+32
        }
    }
    __syncthreads();

    const int lane = tid & 63;
    const int wv   = tid >> 6;
    const int p    = lane & 31;
    const int hi   = lane >> 5;
    const int P    = blockIdx.x * 128 + wv * 32 + p;

    const float2 xv = reinterpret_cast<const float2*>(x)[P];
    const float x0 = xv.x, x1 = xv.y;
    const float bo = b_out[0];

    const float4* sIn4 = reinterpret_cast<const float4*>(sIn);

    float vh[12], vs[12], vt[12], vx[12], vxx[12];

    // ---- input layer (fp32, exact) ----
    #pragma unroll
    for (int r = 0; r < 12; ++r) {
        float4 t = sIn4[hi * 16 + r];
        float z = fmaf(t.x, x0, fmaf(t.y, x1, t.z));
        float e = __expf(2.0f * z);
        float a = 1.0f - __fdividef(2.0f, e + 1.0f);
        float s = fmaf(-a, a, 1.0f);
        float sx = s * t.y;
        vh[r] = a; vt[r] = s * t.x; vx[r] = sx;
        vxx[r] = -2.0f * a * sx * t.y;
    }

    const f32x16 zz = 0.0f;
    const short8* afp = reinterpret_cast<const short8*>(sWf);
    const short8* pz  = reinterpret_cast<const short8*>(sZero);

    for (int layer = 0; layer < NMID; ++layer) {
        const int base = layer * 3 * 64;
        const short8 wh0 = afp[base + lane];
        const short8 wl0 = afp[base + 128 + lane];
        const short8* ph1 = (lane < 32) ? (afp + base + 64 + lane)      : pz;
        const short8* pl1 = (lane < 32) ? (afp + base + 64 + 32 + lane) : pz;
        const short8 wh1 = *ph1;
        const short8 wl1 = *pl1;

        // ---- group 1: H (hi+lo 3-term) and T (single) ----
        {
            u32 dh[8], dhl[8], dt[8];
            build_frags_hl(vh, 0x00003F80u, dh, dhl);   // bias col: hi=1.0, lo=0.0
            build_frags_s(vt, dt);

            f32x16 aH = MF(wh0, dh, 0, zz);  f32x16 aT = MF(wh0, dt, 0, zz);
            aH = MF(wh1, dh, 4, aH);         aT = MF(wh1, dt, 4, aT);
            aH = MF(wh0, dhl, 0, aH);        aT = MF(wl0, dt, 0, aT);
            aH = MF(wh1, dhl, 4, aH);        aT = MF(wl1, dt, 4, aT);
            aH = MF(wl0, dh, 0, aH);
            aH = MF(wl1, dh, 4, aH);

            #pragma unroll
            for (int r = 0; r < 12; ++r) {
                float z = aH[r];
                float e = __expf(2.0f * z);
                float a = 1.0f - __fdividef(2.0f, e + 1.0f);
                float s = fmaf(-a, a, 1.0f);
                vh[r] = a; vs[r] = s; vt[r] = s * aT[r];
            }
        }

        // ---- group 2: X and Q streams (single) ----
        {
            u32 dx[8], dq[8];
            build_frags_s(vx, dx);
            build_frags_s(vxx, dq);

            f32x16 aX = MF(wh0, dx, 0, zz);  f32x16 aQ = MF(wh0, dq, 0, zz);
            aX = MF(wh1, dx, 4, aX);         aQ = MF(wh1, dq, 4, aQ);
            aX = MF(wl0, dx, 0, aX);         aQ = MF(wl0, dq, 0, aQ);
            aX = MF(wl1, dx, 4, aX);         aQ = MF(wl1, dq, 4, aQ);

            #pragma unroll
            for (int r = 0; r < 12; ++r) {
                float zx = aX[r];
                float a = vh[r], s = vs[r];
                float nx = s * zx;
                float t2 = 2.0f * a * nx;
                vx[r] = nx;
                vxx[r] = fmaf(-t2, zx, s * aQ[r]);
            }
        }
    }

    // ---- output layer ----
    float f = 0.f, ft = 0.f, fx = 0.f, fxx = 0.f;
    #pragma unroll
    for (int r = 0; r < 12; ++r) {
        float4 t = sIn4[hi * 16 + r];
        f   = fmaf(t.w, vh[r],  f);
        ft  = fmaf(t.w, vt[r],  ft);
        fx  = fmaf(t.w, vx[r],  fx);
        fxx = fmaf(t.w, vxx[r], fxx);
    }
    f   += __shfl_xor(f, 32);
    ft  += __shfl_xor(ft, 32);
    fx  += __shfl_xor(fx, 32);
    fxx += __shfl_xor(fxx, 32);
    f += bo;

    if (!hi) {
        const float pde = 0.5f * x1 * x1 + ft + 0.5f * fxx + 0.5f * x1 * fx
                          - 0.069444444444444f * fx * fx;
        out[P] = f;
        out[NPTS + P] = pde;
    }
}

extern "C" void kernel_launch(void* const* d_in, const int* in_sizes, int n_in,
                              void* d_out, int out_size, void* d_ws, size_t ws_size,
                              hipStream_t stream) {
    const float* x     = (const float*)d_in[0];
    const float* W_in  = (const float*)d_in[1];
    const float* b_in  = (const float*)d_in[2];
    const float* W_mid = (const float*)d_in[3];
    const float* b_mid = (const float*)d_in[4];
    const float* W_out = (const float*)d_in[5];
    const float* b_out = (const float*)d_in[6];
    float* out = (float*)d_out;

    hipLaunchKernelGGL(pde_mfma_kernel, dim3(NPTS / 128), dim3(256), 0, stream,
                       x, W_in, b_in, W_mid, b_mid, W_out, b_out, out);
}

// Round 14
// 63.251 us; speedup vs baseline: 3.0785x; 1.0261x over previous
//
#include <hip/hip_runtime.h>

#define NPTS 262144
#define HID  20
#define NMID 8

typedef float f32x16 __attribute__((ext_vector_type(16)));
typedef short short8 __attribute__((ext_vector_type(8)));
typedef unsigned int u32;

__device__ __forceinline__ u32 bf16_bits(float f) {
    u32 u = __builtin_bit_cast(u32, f);
    return (u + 0x7FFFu + ((u >> 16) & 1u)) >> 16;   // RNE (weight staging only)
}

// Round-half-up bf16 pair pack: 2 adds + 1 byte-perm. Result = bf16(a) | bf16(b)<<16.
__device__ __forceinline__ u32 pk2(float a, float b) {
    u32 ua = __builtin_bit_cast(u32, a) + 0x8000u;
    u32 ub = __builtin_bit_cast(u32, b) + 0x8000u;
    return __builtin_amdgcn_perm(ub, ua, 0x07060302u);  // bytes: ua[2],ua[3],ub[2],ub[3]
}

// Truncating pack (1 op) — used only for lo-residual words (error ~2^-17 rel).
__device__ __forceinline__ u32 pk2t(float a, float b) {
    return __builtin_amdgcn_perm(__builtin_bit_cast(u32, b),
                                 __builtin_bit_cast(u32, a), 0x07060302u);
}

__device__ __forceinline__ float flo(u32 c) { return __builtin_bit_cast(float, c << 16); }
__device__ __forceinline__ float fhi(u32 c) { return __builtin_bit_cast(float, c & 0xFFFF0000u); }

__device__ __forceinline__ short8 mk_frag(const u32* d, int o) {
    uint4 v = make_uint4(d[o + 0], d[o + 1], d[o + 2], d[o + 3]);
    return __builtin_bit_cast(short8, v);
}

// Weight k-columns PERMUTED at staging (k -> k^12 for k in [4,12)) so the needed
// B-fragment equals the LOCAL C/D register order for both lane halves — no
// cross-lane ops. (hi-lane s=1 slots are k=24..31 where A columns are zero.)
__device__ __forceinline__ void build_frags_hl(const float* v, u32 bias,
                                               u32* bh, u32* bl) {
    u32 h01 = pk2(v[0], v[1]),   h23 = pk2(v[2], v[3]);
    u32 h45 = pk2(v[4], v[5]),   h67 = pk2(v[6], v[7]);
    u32 h89 = pk2(v[8], v[9]),   hAB = pk2(v[10], v[11]);
    bh[0] = h01; bh[1] = h23; bh[2] = h45; bh[3] = h67;
    bh[4] = h89; bh[5] = hAB; bh[6] = bias; bh[7] = 0u;
    bl[0] = pk2t(v[0] - flo(h01), v[1] - fhi(h01));
    bl[1] = pk2t(v[2] - flo(h23), v[3] - fhi(h23));
    bl[2] = pk2t(v[4] - flo(h45), v[5] - fhi(h45));
    bl[3] = pk2t(v[6] - flo(h67), v[7] - fhi(h67));
    bl[4] = pk2t(v[8] - flo(h89), v[9] - fhi(h89));
    bl[5] = pk2t(v[10] - flo(hAB), v[11] - fhi(hAB));
    bl[6] = 0u; bl[7] = 0u;
}

// Derivative streams (T/X/Q): single-bf16 activation fragment (rounded).
__device__ __forceinline__ void build_frags_s(const float* v, u32* bh) {
    bh[0] = pk2(v[0], v[1]);   bh[1] = pk2(v[2], v[3]);
    bh[2] = pk2(v[4], v[5]);   bh[3] = pk2(v[6], v[7]);
    bh[4] = pk2(v[8], v[9]);   bh[5] = pk2(v[10], v[11]);
    bh[6] = 0u; bh[7] = 0u;
}

#define MF(A, D, O, C) __builtin_amdgcn_mfma_f32_32x32x16_bf16(A, mk_frag(D, O), C, 0, 0, 0)

__launch_bounds__(256, 4)
__global__ void pde_mfma_kernel(const float* __restrict__ x,
                                const float* __restrict__ W_in,
                                const float* __restrict__ b_in,
                                const float* __restrict__ W_mid,
                                const float* __restrict__ b_mid,
                                const float* __restrict__ W_out,
                                const float* __restrict__ b_out,
                                float* __restrict__ out) {
    // A-frags, 3 parts/layer (24 KB):
    //   part0 = hi s=0 (64 lanes); part1 = merged s=1 (lanes 0..31 hi, 32..63 lo);
    //   part2 = lo s=0. Lanes>=32 read s=1 frags from a zero block (A rows zero).
    __shared__ short sWf[NMID * 3 * 64 * 8];   // 24 KB
    __shared__ float sIn[2 * 16 * 4];
    __shared__ short sZero[8];

    const int tid = threadIdx.x;

    for (int idx = tid; idx < NMID * 3 * 64 * 8 / 2; idx += 256)
        ((u32*)sWf)[idx] = 0u;
    if (tid < 4) ((u32*)sZero)[tid] = 0u;
    for (int idx = tid; idx < 32; idx += 256) {
        int h2 = idx >> 4, reg = idx & 15;
        int n = (reg & 3) + 8 * (reg >> 2) + 4 * h2;
        float w0 = 0.f, w1 = 0.f, b = 0.f, wo = 0.f;
        if (n < HID) { w0 = W_in[n * 2]; w1 = W_in[n * 2 + 1]; b = b_in[n]; wo = W_out[n]; }
        sIn[idx * 4 + 0] = w0; sIn[idx * 4 + 1] = w1;
        sIn[idx * 4 + 2] = b;  sIn[idx * 4 + 3] = wo;
    }
    __syncthreads();
    for (int idx = tid; idx < NMID * HID * (HID + 1); idx += 256) {
        int layer = idx / (HID * (HID + 1));
        int rem   = idx % (HID * (HID + 1));
        int j = rem / (HID + 1);
        int k = rem % (HID + 1);
        float w = (k < HID) ? W_mid[(layer * HID + j) * HID + k] : b_mid[layer * HID + j];
        u32 whib = bf16_bits(w);
        u32 wlob = bf16_bits(w - __builtin_bit_cast(float, whib << 16));
        int kp = (k >= 4 && k < 12) ? (k ^ 12) : k;   // column permutation
        int s = kp >> 4, kk = kp & 15, h2 = kk >> 3, r = kk & 7;
        int lane = j + 32 * h2;
        if (s == 0) {
            sWf[((layer * 3 + 0) * 64 + lane) * 8 + r] = (short)whib;   // hi s0
            sWf[((layer * 3 + 2) * 64 + lane) * 8 + r] = (short)wlob;   // lo s0
        } else {
            sWf[((layer * 3 + 1) * 64 + lane) * 8 + r]      = (short)whib;  // hi s1
            sWf[((layer * 3 + 1) * 64 + lane + 32) * 8 + r] = (short)wlob;  // lo s1
        }
    }
    __syncthreads();

    const int lane = tid & 63;
    const int wv   = tid >> 6;
    const int p    = lane & 31;
    const int hi   = lane >> 5;
    const int P    = blockIdx.x * 128 + wv * 32 + p;

    const float2 xv = reinterpret_cast<const float2*>(x)[P];
    const float x0 = xv.x, x1 = xv.y;
    const float bo = b_out[0];

    const float4* sIn4 = reinterpret_cast<const float4*>(sIn);

    float vh[12], vs[12], vt[12], vx[12], vxx[12];

    // ---- input layer (fp32, exact) ----
    #pragma unroll
    for (int r = 0; r < 12; ++r) {
        float4 t = sIn4[hi * 16 + r];
        float z = fmaf(t.x, x0, fmaf(t.y, x1, t.z));
        float e = __expf(z + z);
        float rc = __fdividef(1.0f, e + 1.0f);
        float a = fmaf(-2.0f, rc, 1.0f);
        float s = fmaf(-a, a, 1.0f);
        float sx = s * t.y;
        vh[r] = a; vt[r] = s * t.x; vx[r] = sx;
        vxx[r] = -2.0f * a * sx * t.y;
    }

    const f32x16 zz = 0.0f;
    const short8* afp = reinterpret_cast<const short8*>(sWf);
    const short8* pz  = reinterpret_cast<const short8*>(sZero);

    for (int layer = 0; layer < NMID; ++layer) {
        const int base = layer * 3 * 64;
        const short8 wh0 = afp[base + lane];
        const short8 wl0 = afp[base + 128 + lane];
        const short8* ph1 = (lane < 32) ? (afp + base + 64 + lane)      : pz;
        const short8* pl1 = (lane < 32) ? (afp + base + 64 + 32 + lane) : pz;
        const short8 wh1 = *ph1;
        const short8 wl1 = *pl1;

        // ---- phase 1: H fragments + H MFMAs (only aH live) ----
        u32 dh[8], dhl[8];
        build_frags_hl(vh, 0x00003F80u, dh, dhl);   // bias col: hi=1.0, lo=0.0
        f32x16 aH = MF(wh0, dh, 0, zz);
        aH = MF(wh1, dh, 4, aH);
        aH = MF(wh0, dhl, 0, aH);
        aH = MF(wh1, dhl, 4, aH);
        aH = MF(wl0, dh, 0, aH);
        aH = MF(wl1, dh, 4, aH);

        // pack T early (from previous-layer vt; independent of aH)
        u32 dt[8];
        build_frags_s(vt, dt);

        // ---- phase 2: tanh (consumes aH) ----
        #pragma unroll
        for (int r = 0; r < 12; ++r) {
            float z = aH[r];
            float e = __expf(z + z);
            float rc = __fdividef(1.0f, e + 1.0f);
            float a = fmaf(-2.0f, rc, 1.0f);
            vh[r] = a; vs[r] = fmaf(-a, a, 1.0f);
        }
        __builtin_amdgcn_sched_barrier(0);   // keep T MFMAs below aH consumption

        // ---- phase 3: T MFMAs + consume (only aT live) ----
        f32x16 aT = MF(wh0, dt, 0, zz);
        aT = MF(wh1, dt, 4, aT);
        aT = MF(wl0, dt, 0, aT);
        aT = MF(wl1, dt, 4, aT);
        #pragma unroll
        for (int r = 0; r < 12; ++r) vt[r] = vs[r] * aT[r];

        // pack X/Q (from previous-layer vx, vxx)
        u32 dx[8], dq[8];
        build_frags_s(vx, dx);
        build_frags_s(vxx, dq);
        __builtin_amdgcn_sched_barrier(0);   // keep X/Q MFMAs below aT consumption

        // ---- phase 4: X and Q MFMAs + pointwise (aX+aQ live = 32) ----
        f32x16 aX = MF(wh0, dx, 0, zz);  f32x16 aQ = MF(wh0, dq, 0, zz);
        aX = MF(wh1, dx, 4, aX);         aQ = MF(wh1, dq, 4, aQ);
        aX = MF(wl0, dx, 0, aX);         aQ = MF(wl0, dq, 0, aQ);
        aX = MF(wl1, dx, 4, aX);         aQ = MF(wl1, dq, 4, aQ);

        #pragma unroll
        for (int r = 0; r < 12; ++r) {
            float zx = aX[r];
            float a = vh[r], s = vs[r];
            float nx = s * zx;
            float t2 = 2.0f * a * nx;
            vx[r] = nx;
            vxx[r] = fmaf(-t2, zx, s * aQ[r]);
        }
    }

    // ---- output layer ----
    float f = 0.f, ft = 0.f, fx = 0.f, fxx = 0.f;
    #pragma unroll
    for (int r = 0; r < 12; ++r) {
        float4 t = sIn4[hi * 16 + r];
        f   = fmaf(t.w, vh[r],  f);
        ft  = fmaf(t.w, vt[r],  ft);
        fx  = fmaf(t.w, vx[r],  fx);
        fxx = fmaf(t.w, vxx[r], fxx);
    }
    f   += __shfl_xor(f, 32);
    ft  += __shfl_xor(ft, 32);
    fx  += __shfl_xor(fx, 32);
    fxx += __shfl_xor(fxx, 32);
    f += bo;

    if (!hi) {
        const float pde = 0.5f * x1 * x1 + ft + 0.5f * fxx + 0.5f * x1 * fx
                          - 0.069444444444444f * fx * fx;
        out[P] = f;
        out[NPTS + P] = pde;
    }
}

extern "C" void kernel_launch(void* const* d_in, const int* in_sizes, int n_in,
                              void* d_out, int out_size, void* d_ws, size_t ws_size,
                              hipStream_t stream) {
    const float* x     = (const float*)d_in[0];
    const float* W_in  = (const float*)d_in[1];
    const float* b_in  = (const float*)d_in[2];
    const float* W_mid = (const float*)d_in[3];
    const float* b_mid = (const float*)d_in[4];
    const float* W_out = (const float*)d_in[5];
    const float* b_out = (const float*)d_in[6];
    float* out = (float*)d_out;

    hipLaunchKernelGGL(pde_mfma_kernel, dim3(NPTS / 128), dim3(256), 0, stream,
                       x, W_in, b_in, W_mid, b_mid, W_out, b_out, out);
}

// Round 16
// 62.452 us; speedup vs baseline: 3.1179x; 1.0128x over previous
//
#include <hip/hip_runtime.h>

#define NPTS 262144
#define HID  20
#define NMID 8

typedef float f32x16 __attribute__((ext_vector_type(16)));
typedef short short8 __attribute__((ext_vector_type(8)));
typedef unsigned int u32;

__device__ __forceinline__ u32 bf16_bits(float f) {
    u32 u = __builtin_bit_cast(u32, f);
    return (u + 0x7FFFu + ((u >> 16) & 1u)) >> 16;   // RNE (weight staging only)
}

// Round-half-up bf16 pair pack: 2 adds + 1 byte-perm (unbiased-ish; REQUIRED for
// activation fragments — truncation bias compounds across layers, R15 lesson).
__device__ __forceinline__ u32 pk2(float a, float b) {
    u32 ua = __builtin_bit_cast(u32, a) + 0x8000u;
    u32 ub = __builtin_bit_cast(u32, b) + 0x8000u;
    return __builtin_amdgcn_perm(ub, ua, 0x07060302u);  // bytes: ua[2],ua[3],ub[2],ub[3]
}

// Truncating pack (1 op) — lo-residual words only (residual is sign-symmetric).
__device__ __forceinline__ u32 pk2t(float a, float b) {
    return __builtin_amdgcn_perm(__builtin_bit_cast(u32, b),
                                 __builtin_bit_cast(u32, a), 0x07060302u);
}

__device__ __forceinline__ float flo(u32 c) { return __builtin_bit_cast(float, c << 16); }
__device__ __forceinline__ float fhi(u32 c) { return __builtin_bit_cast(float, c & 0xFFFF0000u); }

__device__ __forceinline__ short8 mk_frag4(u32 a, u32 b, u32 c, u32 d) {
    uint4 v = make_uint4(a, b, c, d);
    return __builtin_bit_cast(short8, v);
}

#define MF2(A, B, C) __builtin_amdgcn_mfma_f32_32x32x16_bf16(A, B, C, 0, 0, 0)

__launch_bounds__(256, 4)
__global__ void pde_mfma_kernel(const float* __restrict__ x,
                                const float* __restrict__ W_in,
                                const float* __restrict__ b_in,
                                const float* __restrict__ W_mid,
                                const float* __restrict__ b_mid,
                                const float* __restrict__ W_out,
                                const float* __restrict__ b_out,
                                float* __restrict__ out) {
    // A-frags, 3 parts/layer (24 KB):
    //   part0 = hi s=0 (64 lanes); part1 = merged s=1 (lanes 0..31 hi, 32..63 lo);
    //   part2 = lo s=0. Lanes>=32 read s=1 frags from a zero block (A rows zero).
    // Weight k-columns permuted (k -> k^12 for k in [4,12)) so B-frags equal the
    // local C/D register order for both lane halves — no cross-lane ops.
    __shared__ short sWf[NMID * 3 * 64 * 8];   // 24 KB
    __shared__ float sIn[2 * 16 * 4];
    __shared__ short sZero[8];

    const int tid = threadIdx.x;

    for (int idx = tid; idx < NMID * 3 * 64 * 8 / 2; idx += 256)
        ((u32*)sWf)[idx] = 0u;
    if (tid < 4) ((u32*)sZero)[tid] = 0u;
    for (int idx = tid; idx < 32; idx += 256) {
        int h2 = idx >> 4, reg = idx & 15;
        int n = (reg & 3) + 8 * (reg >> 2) + 4 * h2;
        float w0 = 0.f, w1 = 0.f, b = 0.f, wo = 0.f;
        if (n < HID) { w0 = W_in[n * 2]; w1 = W_in[n * 2 + 1]; b = b_in[n]; wo = W_out[n]; }
        sIn[idx * 4 + 0] = w0; sIn[idx * 4 + 1] = w1;
        sIn[idx * 4 + 2] = b;  sIn[idx * 4 + 3] = wo;
    }
    __syncthreads();
    for (int idx = tid; idx < NMID * HID * (HID + 1); idx += 256) {
        int layer = idx / (HID * (HID + 1));
        int rem   = idx % (HID * (HID + 1));
        int j = rem / (HID + 1);
        int k = rem % (HID + 1);
        float w = (k < HID) ? W_mid[(layer * HID + j) * HID + k] : b_mid[layer * HID + j];
        u32 whib = bf16_bits(w);
        u32 wlob = bf16_bits(w - __builtin_bit_cast(float, whib << 16));
        int kp = (k >= 4 && k < 12) ? (k ^ 12) : k;   // column permutation
        int s = kp >> 4, kk = kp & 15, h2 = kk >> 3, r = kk & 7;
        int lane = j + 32 * h2;
        if (s == 0) {
            sWf[((layer * 3 + 0) * 64 + lane) * 8 + r] = (short)whib;   // hi s0
            sWf[((layer * 3 + 2) * 64 + lane) * 8 + r] = (short)wlob;   // lo s0
        } else {
            sWf[((layer * 3 + 1) * 64 + lane) * 8 + r]      = (short)whib;  // hi s1
            sWf[((layer * 3 + 1) * 64 + lane + 32) * 8 + r] = (short)wlob;  // lo s1
        }
    }
    __syncthreads();

    const int lane = tid & 63;
    const int wv   = tid >> 6;
    const int p    = lane & 31;
    const int hi   = lane >> 5;
    const int P    = blockIdx.x * 128 + wv * 32 + p;

    const float2 xv = reinterpret_cast<const float2*>(x)[P];
    const float x0 = xv.x, x1 = xv.y;
    const float bo = b_out[0];

    const float4* sIn4 = reinterpret_cast<const float4*>(sIn);

    float vh[12], vs[12], vt[12], vx[12], vxx[12];

    // ---- input layer (fp32, exact) ----
    #pragma unroll
    for (int r = 0; r < 12; ++r) {
        float4 t = sIn4[hi * 16 + r];
        float z = fmaf(t.x, x0, fmaf(t.y, x1, t.z));
        float e = __expf(z + z);
        float rc = __fdividef(1.0f, e + 1.0f);
        float a = fmaf(-2.0f, rc, 1.0f);
        float s = fmaf(-a, a, 1.0f);
        float sx = s * t.y;
        vh[r] = a; vt[r] = s * t.x; vx[r] = sx;
        vxx[r] = -2.0f * a * sx * t.y;
    }

    const f32x16 zz = 0.0f;
    const short8* afp = reinterpret_cast<const short8*>(sWf);
    const short8* pz  = reinterpret_cast<const short8*>(sZero);

    // s=1 pointers hoisted: stride 192 short8s/layer for lanes<32, 0 (zero block)
    // for lanes>=32 (their s=1 A-rows are zero).
    const short8* s1h = (lane < 32) ? (afp + 64 + lane)      : pz;
    const short8* s1l = (lane < 32) ? (afp + 64 + 32 + lane) : pz;
    const int s1stride = (lane < 32) ? 192 : 0;

    for (int layer = 0; layer < NMID; ++layer) {
        const int base = layer * 3 * 64;
        const short8 wh0 = afp[base + lane];
        const short8 wl0 = afp[base + 128 + lane];
        const short8 wh1 = s1h[layer * s1stride];
        const short8 wl1 = s1l[layer * s1stride];

        // ---- phase 1: H fragments (built ONCE as short8) + H MFMAs ----
        u32 h01 = pk2(vh[0], vh[1]),  h23 = pk2(vh[2], vh[3]);
        u32 h45 = pk2(vh[4], vh[5]),  h67 = pk2(vh[6], vh[7]);
        u32 h89 = pk2(vh[8], vh[9]),  hAB = pk2(vh[10], vh[11]);
        const short8 bH0 = mk_frag4(h01, h23, h45, h67);
        const short8 bH1 = mk_frag4(h89, hAB, 0x00003F80u, 0u);   // bias col = 1.0
        const short8 bL0 = mk_frag4(
            pk2t(vh[0] - flo(h01), vh[1] - fhi(h01)),
            pk2t(vh[2] - flo(h23), vh[3] - fhi(h23)),
            pk2t(vh[4] - flo(h45), vh[5] - fhi(h45)),
            pk2t(vh[6] - flo(h67), vh[7] - fhi(h67)));
        const short8 bL1 = mk_frag4(
            pk2t(vh[8] - flo(h89), vh[9] - fhi(h89)),
            pk2t(vh[10] - flo(hAB), vh[11] - fhi(hAB)), 0u, 0u);

        f32x16 aH = MF2(wh0, bH0, zz);
        aH = MF2(wh1, bH1, aH);
        aH = MF2(wh0, bL0, aH);
        aH = MF2(wh1, bL1, aH);
        aH = MF2(wl0, bH0, aH);
        aH = MF2(wl1, bH1, aH);

        // pack T early (from previous-layer vt; independent of aH)
        const short8 bT0 = mk_frag4(pk2(vt[0], vt[1]), pk2(vt[2], vt[3]),
                                    pk2(vt[4], vt[5]), pk2(vt[6], vt[7]));
        const short8 bT1 = mk_frag4(pk2(vt[8], vt[9]), pk2(vt[10], vt[11]), 0u, 0u);

        // ---- phase 2: tanh (consumes aH) ----
        #pragma unroll
        for (int r = 0; r < 12; ++r) {
            float z = aH[r];
            float e = __expf(z + z);
            float rc = __fdividef(1.0f, e + 1.0f);
            float a = fmaf(-2.0f, rc, 1.0f);
            vh[r] = a; vs[r] = fmaf(-a, a, 1.0f);
        }
        __builtin_amdgcn_sched_barrier(0);   // keep T MFMAs below aH consumption

        // ---- phase 3: T MFMAs + consume (only aT live) ----
        f32x16 aT = MF2(wh0, bT0, zz);
        aT = MF2(wh1, bT1, aT);
        aT = MF2(wl0, bT0, aT);
        aT = MF2(wl1, bT1, aT);
        #pragma unroll
        for (int r = 0; r < 12; ++r) vt[r] = vs[r] * aT[r];

        // pack X/Q (from previous-layer vx, vxx)
        const short8 bX0 = mk_frag4(pk2(vx[0], vx[1]), pk2(vx[2], vx[3]),
                                    pk2(vx[4], vx[5]), pk2(vx[6], vx[7]));
        const short8 bX1 = mk_frag4(pk2(vx[8], vx[9]), pk2(vx[10], vx[11]), 0u, 0u);
        const short8 bQ0 = mk_frag4(pk2(vxx[0], vxx[1]), pk2(vxx[2], vxx[3]),
                                    pk2(vxx[4], vxx[5]), pk2(vxx[6], vxx[7]));
        const short8 bQ1 = mk_frag4(pk2(vxx[8], vxx[9]), pk2(vxx[10], vxx[11]), 0u, 0u);
        __builtin_amdgcn_sched_barrier(0);   // keep X/Q MFMAs below aT consumption

        // ---- phase 4: X and Q MFMAs + pointwise (aX+aQ live = 32) ----
        f32x16 aX = MF2(wh0, bX0, zz);   f32x16 aQ = MF2(wh0, bQ0, zz);
        aX = MF2(wh1, bX1, aX);          aQ = MF2(wh1, bQ1, aQ);
        aX = MF2(wl0, bX0, aX);          aQ = MF2(wl0, bQ0, aQ);
        aX = MF2(wl1, bX1, aX);          aQ = MF2(wl1, bQ1, aQ);

        #pragma unroll
        for (int r = 0; r < 12; ++r) {
            float zx = aX[r];
            float a = vh[r], s = vs[r];
            float nx = s * zx;
            float t2 = 2.0f * a * nx;
            vx[r] = nx;
            vxx[r] = fmaf(-t2, zx, s * aQ[r]);
        }
    }

    // ---- output layer ----
    float f = 0.f, ft = 0.f, fx = 0.f, fxx = 0.f;
    #pragma unroll
    for (int r = 0; r < 12; ++r) {
        float4 t = sIn4[hi * 16 + r];
        f   = fmaf(t.w, vh[r],  f);
        ft  = fmaf(t.w, vt[r],  ft);
        fx  = fmaf(t.w, vx[r],  fx);
        fxx = fmaf(t.w, vxx[r], fxx);
    }
    f   += __shfl_xor(f, 32);
    ft  += __shfl_xor(ft, 32);
    fx  += __shfl_xor(fx, 32);
    fxx += __shfl_xor(fxx, 32);
    f += bo;

    if (!hi) {
        const float pde = 0.5f * x1 * x1 + ft + 0.5f * fxx + 0.5f * x1 * fx
                          - 0.069444444444444f * fx * fx;
        out[P] = f;
        out[NPTS + P] = pde;
    }
}

extern "C" void kernel_launch(void* const* d_in, const int* in_sizes, int n_in,
                              void* d_out, int out_size, void* d_ws, size_t ws_size,
                              hipStream_t stream) {
    const float* x     = (const float*)d_in[0];
    const float* W_in  = (const float*)d_in[1];
    const float* b_in  = (const float*)d_in[2];
    const float* W_mid = (const float*)d_in[3];
    const float* b_mid = (const float*)d_in[4];
    const float* W_out = (const float*)d_in[5];
    const float* b_out = (const float*)d_in[6];
    float* out = (float*)d_out;

    hipLaunchKernelGGL(pde_mfma_kernel, dim3(NPTS / 128), dim3(256), 0, stream,
                       x, W_in, b_in, W_mid, b_mid, W_out, b_out, out);
}

// Round 18
// 51.844 us; speedup vs baseline: 3.7558x; 1.2046x over previous
//
#include <hip/hip_runtime.h>

#define NPTS 262144
#define HID  20
#define NMID 8

typedef float f32x16 __attribute__((ext_vector_type(16)));
typedef _Float16 half8 __attribute__((ext_vector_type(8)));
typedef _Float16 half2v __attribute__((ext_vector_type(2)));
typedef __fp16 fp16x2 __attribute__((ext_vector_type(2)));
typedef unsigned int u32;

// RNE fp16 pair pack (2 cvt + pack) — value (H) stream.
__device__ __forceinline__ u32 pkh_rne(float a, float b) {
    half2v r; r.x = (_Float16)a; r.y = (_Float16)b;
    return __builtin_bit_cast(u32, r);
}
// RTZ fp16 pair pack (1 op, v_cvt_pkrtz_f16_f32) — derivative streams
// (bias 2^-12, coherent over 8 layers ~0.2%; R15's bf16-RTZ failure was 2^-9).
__device__ __forceinline__ u32 pkh_rtz(float a, float b) {
    fp16x2 r = __builtin_amdgcn_cvt_pkrtz(a, b);
    return __builtin_bit_cast(u32, r);
}

__device__ __forceinline__ half8 mk_fragh(u32 a, u32 b, u32 c, u32 d) {
    uint4 v = make_uint4(a, b, c, d);
    return __builtin_bit_cast(half8, v);
}

#define MF2(A, B, C) __builtin_amdgcn_mfma_f32_32x32x16_f16(A, B, C, 0, 0, 0)

__launch_bounds__(256, 4)
__global__ void pde_mfma_kernel(const float* __restrict__ x,
                                const float* __restrict__ W_in,
                                const float* __restrict__ b_in,
                                const float* __restrict__ W_mid,
                                const float* __restrict__ b_mid,
                                const float* __restrict__ W_out,
                                const float* __restrict__ b_out,
                                float* __restrict__ out) {
    // fp16 A-frags, 3 parts/layer (24 KB):
    //   part0 = hi s=0 (64 lanes); part1 = merged s=1 (lanes 0..31 hi, 32..63 lo);
    //   part2 = lo s=0. Lanes>=32 read s=1 frags from a zero block (A rows zero).
    // Weight k-columns permuted (k -> k^12 for k in [4,12)) so B-frags equal the
    // local C/D register order for both lane halves — no cross-lane ops.
    // H stream: hi+lo fp16 weights (21-bit effective). T/X/Q: hi only (11-bit).
    __shared__ short sWf[NMID * 3 * 64 * 8];   // 24 KB
    __shared__ float sIn[2 * 16 * 4];
    __shared__ short sZero[8];

    const int tid = threadIdx.x;

    for (int idx = tid; idx < NMID * 3 * 64 * 8 / 2; idx += 256)
        ((u32*)sWf)[idx] = 0u;
    if (tid < 4) ((u32*)sZero)[tid] = 0u;
    for (int idx = tid; idx < 32; idx += 256) {
        int h2 = idx >> 4, reg = idx & 15;
        int n = (reg & 3) + 8 * (reg >> 2) + 4 * h2;
        float w0 = 0.f, w1 = 0.f, b = 0.f, wo = 0.f;
        if (n < HID) { w0 = W_in[n * 2]; w1 = W_in[n * 2 + 1]; b = b_in[n]; wo = W_out[n]; }
        sIn[idx * 4 + 0] = w0; sIn[idx * 4 + 1] = w1;
        sIn[idx * 4 + 2] = b;  sIn[idx * 4 + 3] = wo;
    }
    __syncthreads();
    for (int idx = tid; idx < NMID * HID * (HID + 1); idx += 256) {
        int layer = idx / (HID * (HID + 1));
        int rem   = idx % (HID * (HID + 1));
        int j = rem / (HID + 1);
        int k = rem % (HID + 1);
        float w = (k < HID) ? W_mid[(layer * HID + j) * HID + k] : b_mid[layer * HID + j];
        _Float16 whf = (_Float16)w;                       // RNE
        _Float16 wlf = (_Float16)(w - (float)whf);        // exact residual, RNE
        short whib = (short)__builtin_bit_cast(unsigned short, whf);
        short wlob = (short)__builtin_bit_cast(unsigned short, wlf);
        int kp = (k >= 4 && k < 12) ? (k ^ 12) : k;   // column permutation
        int s = kp >> 4, kk = kp & 15, h2 = kk >> 3, r = kk & 7;
        int lane = j + 32 * h2;
        if (s == 0) {
            sWf[((layer * 3 + 0) * 64 + lane) * 8 + r] = whib;   // hi s0
            sWf[((layer * 3 + 2) * 64 + lane) * 8 + r] = wlob;   // lo s0
        } else {
            sWf[((layer * 3 + 1) * 64 + lane) * 8 + r]      = whib;  // hi s1
            sWf[((layer * 3 + 1) * 64 + lane + 32) * 8 + r] = wlob;  // lo s1
        }
    }
    __syncthreads();

    const int lane = tid & 63;
    const int wv   = tid >> 6;
    const int p    = lane & 31;
    const int hi   = lane >> 5;
    const int P    = blockIdx.x * 128 + wv * 32 + p;

    const float2 xv = reinterpret_cast<const float2*>(x)[P];
    const float x0 = xv.x, x1 = xv.y;
    const float bo = b_out[0];

    const float4* sIn4 = reinterpret_cast<const float4*>(sIn);

    float vh[12], vs[12], vt[12], vx[12], vxx[12];

    // ---- input layer (fp32, exact) ----
    #pragma unroll
    for (int r = 0; r < 12; ++r) {
        float4 t = sIn4[hi * 16 + r];
        float z = fmaf(t.x, x0, fmaf(t.y, x1, t.z));
        float e = __expf(z + z);
        float rc = __fdividef(1.0f, e + 1.0f);
        float a = fmaf(-2.0f, rc, 1.0f);
        float s = fmaf(-a, a, 1.0f);
        float sx = s * t.y;
        vh[r] = a; vt[r] = s * t.x; vx[r] = sx;
        vxx[r] = -2.0f * a * sx * t.y;
    }

    const f32x16 zz = 0.0f;
    const half8* afp = reinterpret_cast<const half8*>(sWf);
    const half8* pz  = reinterpret_cast<const half8*>(sZero);

    // s=1 pointers hoisted: stride 192 half8s/layer for lanes<32, 0 (zero block)
    // for lanes>=32 (their s=1 A-rows are zero).
    const half8* s1h = (lane < 32) ? (afp + 64 + lane)      : pz;
    const half8* s1l = (lane < 32) ? (afp + 64 + 32 + lane) : pz;
    const int s1stride = (lane < 32) ? 192 : 0;

    for (int layer = 0; layer < NMID; ++layer) {
        const int base = layer * 3 * 64;
        const half8 wh0 = afp[base + lane];
        const half8 wl0 = afp[base + 128 + lane];
        const half8 wh1 = s1h[layer * s1stride];
        const half8 wl1 = s1l[layer * s1stride];

        // ---- phase 1: H fragments (fp16 RNE) + 4 H MFMAs (hi+lo weights) ----
        const half8 bH0 = mk_fragh(pkh_rne(vh[0], vh[1]), pkh_rne(vh[2], vh[3]),
                                   pkh_rne(vh[4], vh[5]), pkh_rne(vh[6], vh[7]));
        const half8 bH1 = mk_fragh(pkh_rne(vh[8], vh[9]), pkh_rne(vh[10], vh[11]),
                                   0x00003C00u, 0u);      // bias col k=20 = 1.0 fp16
        f32x16 aH = MF2(wh0, bH0, zz);
        aH = MF2(wh1, bH1, aH);
        aH = MF2(wl0, bH0, aH);
        aH = MF2(wl1, bH1, aH);

        // pack T early (from previous-layer vt; independent of aH)
        const half8 bT0 = mk_fragh(pkh_rtz(vt[0], vt[1]), pkh_rtz(vt[2], vt[3]),
                                   pkh_rtz(vt[4], vt[5]), pkh_rtz(vt[6], vt[7]));
        const half8 bT1 = mk_fragh(pkh_rtz(vt[8], vt[9]), pkh_rtz(vt[10], vt[11]),
                                   0u, 0u);

        // ---- phase 2: tanh (consumes aH) ----
        #pragma unroll
        for (int r = 0; r < 12; ++r) {
            float z = aH[r];
            float e = __expf(z + z);
            float rc = __fdividef(1.0f, e + 1.0f);
            float a = fmaf(-2.0f, rc, 1.0f);
            vh[r] = a; vs[r] = fmaf(-a, a, 1.0f);
        }
        __builtin_amdgcn_sched_barrier(0);   // keep T MFMAs below aH consumption

        // ---- phase 3: T MFMAs (hi weights only) + consume ----
        f32x16 aT = MF2(wh0, bT0, zz);
        aT = MF2(wh1, bT1, aT);
        #pragma unroll
        for (int r = 0; r < 12; ++r) vt[r] = vs[r] * aT[r];

        // pack X/Q (from previous-layer vx, vxx)
        const half8 bX0 = mk_fragh(pkh_rtz(vx[0], vx[1]), pkh_rtz(vx[2], vx[3]),
                                   pkh_rtz(vx[4], vx[5]), pkh_rtz(vx[6], vx[7]));
        const half8 bX1 = mk_fragh(pkh_rtz(vx[8], vx[9]), pkh_rtz(vx[10], vx[11]),
                                   0u, 0u);
        const half8 bQ0 = mk_fragh(pkh_rtz(vxx[0], vxx[1]), pkh_rtz(vxx[2], vxx[3]),
                                   pkh_rtz(vxx[4], vxx[5]), pkh_rtz(vxx[6], vxx[7]));
        const half8 bQ1 = mk_fragh(pkh_rtz(vxx[8], vxx[9]), pkh_rtz(vxx[10], vxx[11]),
                                   0u, 0u);
        __builtin_amdgcn_sched_barrier(0);   // keep X/Q MFMAs below aT consumption

        // ---- phase 4: X and Q MFMAs (hi weights only) + pointwise ----
        f32x16 aX = MF2(wh0, bX0, zz);   f32x16 aQ = MF2(wh0, bQ0, zz);
        aX = MF2(wh1, bX1, aX);          aQ = MF2(wh1, bQ1, aQ);

        #pragma unroll
        for (int r = 0; r < 12; ++r) {
            float zx = aX[r];
            float a = vh[r], s = vs[r];
            float nx = s * zx;
            float t2 = 2.0f * a * nx;
            vx[r] = nx;
            vxx[r] = fmaf(-t2, zx, s * aQ[r]);
        }
    }

    // ---- output layer ----
    float f = 0.f, ft = 0.f, fx = 0.f, fxx = 0.f;
    #pragma unroll
    for (int r = 0; r < 12; ++r) {
        float4 t = sIn4[hi * 16 + r];
        f   = fmaf(t.w, vh[r],  f);
        ft  = fmaf(t.w, vt[r],  ft);
        fx  = fmaf(t.w, vx[r],  fx);
        fxx = fmaf(t.w, vxx[r], fxx);
    }
    f   += __shfl_xor(f, 32);
    ft  += __shfl_xor(ft, 32);
    fx  += __shfl_xor(fx, 32);
    fxx += __shfl_xor(fxx, 32);
    f += bo;

    if (!hi) {
        const float pde = 0.5f * x1 * x1 + ft + 0.5f * fxx + 0.5f * x1 * fx
                          - 0.069444444444444f * fx * fx;
        out[P] = f;
        out[NPTS + P] = pde;
    }
}

extern "C" void kernel_launch(void* const* d_in, const int* in_sizes, int n_in,
                              void* d_out, int out_size, void* d_ws, size_t ws_size,
                              hipStream_t stream) {
    const float* x     = (const float*)d_in[0];
    const float* W_in  = (const float*)d_in[1];
    const float* b_in  = (const float*)d_in[2];
    const float* W_mid = (const float*)d_in[3];
    const float* b_mid = (const float*)d_in[4];
    const float* W_out = (const float*)d_in[5];
    const float* b_out = (const float*)d_in[6];
    float* out = (float*)d_out;

    hipLaunchKernelGGL(pde_mfma_kernel, dim3(NPTS / 128), dim3(256), 0, stream,
                       x, W_in, b_in, W_mid, b_mid, W_out, b_out, out);
}